// Round 7
// baseline (428.594 us; speedup 1.0000x reference)
//
#include <hip/hip_runtime.h>
#include <math.h>

#define HIDDEN 4096
#define NEXP   128
#define TOPK   8
#define BT     32                 // tokens per block; grid 512 = 2 blocks/CU
#define CHUNK  64
#define NCHUNK (HIDDEN / CHUNK)   // 64
#define SSTR   132                // epilogue score row stride (doubles)
#define PLANE  (NEXP * CHUNK)     // 8192 bytes per (chunk,slice) W plane

typedef int v4i __attribute__((ext_vector_type(4)));

static __device__ __forceinline__ unsigned pack4(int a, int b, int c, int d) {
    return (unsigned)(a & 255) | ((unsigned)(b & 255) << 8) |
           ((unsigned)(c & 255) << 16) | ((unsigned)(d & 255) << 24);
}

// Balanced base-128 slicing: val = M * sum_i d_i * 2^(-6-7i), |d_i| <= 64.
// scale1 = 2^13 / M. All float steps exact (pow2 mul, rint, Sterbenz sub).
static __device__ __forceinline__ void slice5(float val, float scale1,
        int& d0, int& d1, int& d2, int& d3, int& d4) {
    float v = val * scale1;
    float f = __builtin_rintf(v);
    float r = v - f;                                 // exact
    int nh = (int)f;                                 // |nh| <= 2^13
    int nl = (int)__builtin_rintf(r * 2097152.0f);   // 2^21, |nl| <= 2^20
    d0 = (nh + 64) >> 7;  d1 = nh - (d0 << 7);
    d2 = (nl + 8192) >> 14;
    int r2 = nl - (d2 << 14);
    d3 = (r2 + 64) >> 7;  d4 = r2 - (d3 << 7);
}

static __device__ __forceinline__ void slice4(float val, float scale1,
        int& d0, int& d1, int& d2, int& d3) {
    float v = val * scale1;
    float f = __builtin_rintf(v);
    float r = v - f;
    int nh = (int)f;
    int nl = (int)__builtin_rintf(r * 16384.0f);     // 2^14, |nl| <= 2^13
    d0 = (nh + 64) >> 7;  d1 = nh - (d0 << 7);
    d2 = (nl + 64) >> 7;  d3 = nl - (d2 << 7);
}

// ---------------- W pre-slicing: [c][s][e][64] i8 planes (2.62 MB) ----------
// (router reads slices 0..3; plane 4 is simply unread)
__global__ __launch_bounds__(256)
void slice_w_kernel(const float* __restrict__ W, signed char* __restrict__ P)
{
    const int t  = blockIdx.x * 256 + threadIdx.x;   // 65536 threads
    const int e  = t >> 9;
    const int k0 = (t & 511) * 8;
    const float* src = W + (size_t)e * HIDDEN + k0;
    const float4 a = ((const float4*)src)[0];
    const float4 b = ((const float4*)src)[1];

    // M_w = 0.25 -> scale1 = 2^15
    int p00,p01,p02,p03,p04; slice5(a.x, 32768.0f, p00,p01,p02,p03,p04);
    int p10,p11,p12,p13,p14; slice5(a.y, 32768.0f, p10,p11,p12,p13,p14);
    int p20,p21,p22,p23,p24; slice5(a.z, 32768.0f, p20,p21,p22,p23,p24);
    int p30,p31,p32,p33,p34; slice5(a.w, 32768.0f, p30,p31,p32,p33,p34);
    int p40,p41,p42,p43,p44; slice5(b.x, 32768.0f, p40,p41,p42,p43,p44);
    int p50,p51,p52,p53,p54; slice5(b.y, 32768.0f, p50,p51,p52,p53,p54);
    int p60,p61,p62,p63,p64; slice5(b.z, 32768.0f, p60,p61,p62,p63,p64);
    int p70,p71,p72,p73,p74; slice5(b.w, 32768.0f, p70,p71,p72,p73,p74);

    const int c = k0 >> 6, kin = k0 & 63;
    signed char* base = P + ((size_t)(c * 5) * NEXP + e) * CHUNK + kin;
    uint2 v;
    v.x = pack4(p00,p10,p20,p30); v.y = pack4(p40,p50,p60,p70);
    *(uint2*)(base + 0 * PLANE) = v;
    v.x = pack4(p01,p11,p21,p31); v.y = pack4(p41,p51,p61,p71);
    *(uint2*)(base + 1 * PLANE) = v;
    v.x = pack4(p02,p12,p22,p32); v.y = pack4(p42,p52,p62,p72);
    *(uint2*)(base + 2 * PLANE) = v;
    v.x = pack4(p03,p13,p23,p33); v.y = pack4(p43,p53,p63,p73);
    *(uint2*)(base + 3 * PLANE) = v;
    v.x = pack4(p04,p14,p24,p34); v.y = pack4(p44,p54,p64,p74);
    *(uint2*)(base + 4 * PLANE) = v;
}

// X slicing (M_x = 8 -> scale1 = 2^10): 4 floats -> 4 slice planes of 4 bytes
static __device__ __forceinline__ void slice_store_x4(char* dst, float4 xa)
{
    int a00,a01,a02,a03; slice4(xa.x, 1024.0f, a00,a01,a02,a03);
    int a10,a11,a12,a13; slice4(xa.y, 1024.0f, a10,a11,a12,a13);
    int a20,a21,a22,a23; slice4(xa.z, 1024.0f, a20,a21,a22,a23);
    int a30,a31,a32,a33; slice4(xa.w, 1024.0f, a30,a31,a32,a33);
    *(unsigned*)(dst + 0 * 2048) = pack4(a00, a10, a20, a30);
    *(unsigned*)(dst + 1 * 2048) = pack4(a01, a11, a21, a31);
    *(unsigned*)(dst + 2 * 2048) = pack4(a02, a12, a22, a32);
    *(unsigned*)(dst + 3 * 2048) = pack4(a03, a13, a23, a33);
}

// 13-MFMA pyramid (i+j<=4 minus (a0,b4)); spaced order so same-acc ops are
// >=2 apart (integer accumulation -> order provably bit-identical).
#define MFMA13W(BF, BUF)                                                       \
    {                                                                          \
        _Pragma("unroll")                                                      \
        for (int tt = 0; tt < 2; tt++) {                                       \
            const char* ap = Ast + (BUF) + (tt ? rph1 : rph0);                 \
            const v4i a0 = *(const v4i*)(ap + 0 * 2048);                       \
            const v4i a1 = *(const v4i*)(ap + 1 * 2048);                       \
            const v4i a2 = *(const v4i*)(ap + 2 * 2048);                       \
            const v4i a3 = *(const v4i*)(ap + 3 * 2048);                       \
            acc[tt][0] = __builtin_amdgcn_mfma_i32_16x16x64_i8(a0, BF[0], acc[tt][0], 0, 0, 0); \
            acc[tt][1] = __builtin_amdgcn_mfma_i32_16x16x64_i8(a0, BF[1], acc[tt][1], 0, 0, 0); \
            acc[tt][2] = __builtin_amdgcn_mfma_i32_16x16x64_i8(a0, BF[2], acc[tt][2], 0, 0, 0); \
            acc[tt][3] = __builtin_amdgcn_mfma_i32_16x16x64_i8(a0, BF[3], acc[tt][3], 0, 0, 0); \
            acc[tt][4] = __builtin_amdgcn_mfma_i32_16x16x64_i8(a1, BF[3], acc[tt][4], 0, 0, 0); \
            acc[tt][1] = __builtin_amdgcn_mfma_i32_16x16x64_i8(a1, BF[0], acc[tt][1], 0, 0, 0); \
            acc[tt][2] = __builtin_amdgcn_mfma_i32_16x16x64_i8(a1, BF[1], acc[tt][2], 0, 0, 0); \
            acc[tt][3] = __builtin_amdgcn_mfma_i32_16x16x64_i8(a1, BF[2], acc[tt][3], 0, 0, 0); \
            acc[tt][4] = __builtin_amdgcn_mfma_i32_16x16x64_i8(a2, BF[2], acc[tt][4], 0, 0, 0); \
            acc[tt][2] = __builtin_amdgcn_mfma_i32_16x16x64_i8(a2, BF[0], acc[tt][2], 0, 0, 0); \
            acc[tt][3] = __builtin_amdgcn_mfma_i32_16x16x64_i8(a2, BF[1], acc[tt][3], 0, 0, 0); \
            acc[tt][4] = __builtin_amdgcn_mfma_i32_16x16x64_i8(a3, BF[1], acc[tt][4], 0, 0, 0); \
            acc[tt][3] = __builtin_amdgcn_mfma_i32_16x16x64_i8(a3, BF[0], acc[tt][3], 0, 0, 0); \
        }                                                                      \
    }

// ---------------- main router kernel ---------------------------------------
// 512 threads/block (8 waves): et split 8-ways -> per-wave work halves while
// per-CU B traffic is unchanged; 2 blocks/CU -> 4 waves/SIMD TLP. Pipeline
// skeleton identical to R5 (raw s_barrier + lgkmcnt(0)-only drain; B/X global
// loads stay in flight across barriers; bfE/bfO chunk ping-pong).
__global__ __launch_bounds__(512, 4)
void router_kernel(const float* __restrict__ X,
                   const signed char* __restrict__ P,
                   const float* __restrict__ Bias,
                   float* __restrict__ Out, int T)
{
    __shared__ double S[BT * SSTR];   // 33792 B; first 16 KB doubles as A staging
    char* Ast = (char*)S;             // [buf 8192][slice 2048][unit 16]

    const int tid  = threadIdx.x;
    const int lane = tid & 63;
    const int wave = tid >> 6;        // 0..7 -> expert tile
    const int tokBase = blockIdx.x * BT;

    const int m = lane & 15;
    const int q = lane >> 4;

    // slicing job: token sm, k-run of 4 (512 jobs = 32 tokens x 16 runs)
    const int sm  = tid & 31;
    const int sk4 = tid >> 5;                                 // 0..15
    int srow = tokBase + sm; if (srow >= T) srow = T - 1;
    const float* xptr = X + (size_t)srow * HIDDEN + sk4 * 4;
    const int su    = sm * 4 + (sk4 >> 2);                    // unit = m*4 + k16
    const int swoff = ((su ^ ((su >> 3) & 7)) << 4) + (sk4 & 3) * 4;

    // A-frag LDS read offsets (m, k-quarter q)
    const int ru0  = (m     ) * 4 + q;
    const int ru1  = (m + 16) * 4 + q;
    const int rph0 = (ru0 ^ ((ru0 >> 3) & 7)) << 4;
    const int rph1 = (ru1 ^ ((ru1 >> 3) & 7)) << 4;

    // B global offset: expert = wave*16 + m, k-quarter q
    const size_t boff = (size_t)(wave * 16 + m) * CHUNK + (size_t)q * 16;

    v4i acc[2][5];
    #pragma unroll
    for (int tt = 0; tt < 2; tt++)
        #pragma unroll
        for (int s = 0; s < 5; s++)
            acc[tt][s] = (v4i){0, 0, 0, 0};

    // ---- prologue: slice X[0] -> buf0; issue B[0] and X[1] loads ----------
    {
        float4 xa = *(const float4*)xptr;
        slice_store_x4(Ast + swoff, xa);
    }
    v4i bfE[4], bfO[4];
    #pragma unroll
    for (int s = 0; s < 4; s++)
        bfE[s] = *(const v4i*)(P + (size_t)s * PLANE + boff);
    float4 xo = *(const float4*)(xptr + CHUNK);

    asm volatile("s_waitcnt lgkmcnt(0)" ::: "memory");
    __builtin_amdgcn_s_barrier();

    float4 xe;
    #pragma unroll 1
    for (int c = 0; c < NCHUNK; c += 2) {
        // ---- even chunk c: A = buf0, B = bfE; prefetch B[c+1], X[c+2] -----
        {
            const signed char* pn = P + (size_t)((c + 1) * 5) * PLANE;
            #pragma unroll
            for (int s = 0; s < 4; s++)
                bfO[s] = *(const v4i*)(pn + (size_t)s * PLANE + boff);
            xe = *(const float4*)(xptr + ((c + 2) & (NCHUNK - 1)) * CHUNK);

            MFMA13W(bfE, 0)

            slice_store_x4(Ast + 8192 + swoff, xo);        // A[c+1] -> buf1
            asm volatile("s_waitcnt lgkmcnt(0)" ::: "memory");
            __builtin_amdgcn_s_barrier();
        }
        // ---- odd chunk c+1: A = buf1, B = bfO; prefetch B[c+2], X[c+3] ----
        {
            const signed char* pn = P + (size_t)(((c + 2) & (NCHUNK - 1)) * 5) * PLANE;
            #pragma unroll
            for (int s = 0; s < 4; s++)
                bfE[s] = *(const v4i*)(pn + (size_t)s * PLANE + boff);
            xo = *(const float4*)(xptr + ((c + 3) & (NCHUNK - 1)) * CHUNK);

            MFMA13W(bfO, 8192)

            if (c + 2 < NCHUNK)
                slice_store_x4(Ast + swoff, xe);           // A[c+2] -> buf0
            asm volatile("s_waitcnt lgkmcnt(0)" ::: "memory");
            __builtin_amdgcn_s_barrier();
        }
    }

    // ---- epilogue: exact f64 digit combine, sigmoid + bias -> LDS ----------
    {
        const double w0 = 0x1p-11, w1 = 0x1p-18, w2 = 0x1p-25, w3 = 0x1p-32, w4 = 0x1p-39;
        const int ecol = wave * 16 + m;
        const double bias = (double)Bias[ecol];
        #pragma unroll
        for (int tt = 0; tt < 2; tt++) {
            #pragma unroll
            for (int r = 0; r < 4; r++) {
                const int trow = tt * 16 + q * 4 + r;
                const double logit = (double)acc[tt][0][r] * w0
                                   + (double)acc[tt][1][r] * w1
                                   + (double)acc[tt][2][r] * w2
                                   + (double)acc[tt][3][r] * w3
                                   + (double)acc[tt][4][r] * w4;
                S[trow * SSTR + ecol] = 1.0 / (1.0 + exp(-logit)) + bias;
            }
        }
    }
    __syncthreads();

    // ---- parallel top-8: 8 lanes per token, stable (lowest index on ties) --
    if (tid < BT * 8) {
        const int tk  = tid >> 3;        // token within block: 0..31
        const int j   = tid & 7;         // 16-expert group:    0..7
        const int tok = tokBase + tk;
        const double* row = S + tk * SSTR + j * 16;
        double v[16];
        #pragma unroll
        for (int k = 0; k < 16; k++) v[k] = row[k];

        double wts[TOPK]; float idxf[TOPK];
        double wsum = 0.0;
        #pragma unroll
        for (int p = 0; p < TOPK; p++) {
            // local argmax over 16 (ascending strict > -> lowest index wins)
            double best = v[0]; int bi = 0;
            #pragma unroll
            for (int k = 1; k < 16; k++)
                if (v[k] > best) { best = v[k]; bi = k; }
            int be = j * 16 + bi;
            // 8-lane butterfly argmax; tie -> lower expert index
            #pragma unroll
            for (int off = 1; off < 8; off <<= 1) {
                double ob = __shfl_xor(best, off, 8);
                int    oe = __shfl_xor(be,   off, 8);
                if (ob > best || (ob == best && oe < be)) { best = ob; be = oe; }
            }
            // suppress the winner (static indexing -> cndmask, no scratch)
            const bool own = (be >> 4) == j;
            const int  bl  = be & 15;
            #pragma unroll
            for (int k = 0; k < 16; k++)
                if (own && k == bl) v[k] = -1.0e300;
            const double sg = best - (double)Bias[be];
            wts[p]  = sg;
            wsum   += sg;
            idxf[p] = (float)be;
        }
        if (j == 0 && tok < T) {
            const double inv = 1.0 / (wsum + 1e-20);
            float* oi = Out + (size_t)tok * TOPK;
            float* ow = Out + (size_t)T * TOPK + (size_t)tok * TOPK;
            #pragma unroll
            for (int p = 0; p < TOPK; p++) {
                oi[p] = idxf[p];
                ow[p] = (float)(wts[p] * inv);
            }
        }
    }
}

extern "C" void kernel_launch(void* const* d_in, const int* in_sizes, int n_in,
                              void* d_out, int out_size, void* d_ws, size_t ws_size,
                              hipStream_t stream) {
    const float* X    = (const float*)d_in[0];
    const float* W    = (const float*)d_in[1];
    const float* Bias = (const float*)d_in[2];
    float* Out = (float*)d_out;
    const int T = in_sizes[0] / HIDDEN;
    signed char* P = (signed char*)d_ws;   // 2.62 MB of workspace

    hipLaunchKernelGGL(slice_w_kernel, dim3(NEXP * 512 / 256), dim3(256), 0, stream, W, P);
    hipLaunchKernelGGL(router_kernel, dim3((T + BT - 1) / BT), dim3(512), 0, stream,
                       X, P, Bias, Out, T);
}